// Round 5
// baseline (3277.168 us; speedup 1.0000x reference)
//
#include <hip/hip_runtime.h>
#include <hip/hip_bf16.h>
#include <math.h>

constexpr int NE = 400000;
constexpr int NN = 40000;
constexpr int CD = 64;
constexpr int ZK = 131;   // 2*64 + 3
constexpr int WST = 132;  // padded stride
constexpr int NGRAPH = 64;

// ---------------- fc1: x0 = relu(x @ fc1_w + b) ----------------
__global__ void k_fc1(const float* __restrict__ x,
                      const float* __restrict__ w,
                      const float* __restrict__ b,
                      float* __restrict__ out) {
    int i = blockIdx.x * 256 + threadIdx.x;
    if (i >= NN * CD) return;
    int n = i >> 6, c = i & 63;
    float acc = b[c];
    #pragma unroll
    for (int k = 0; k < 9; ++k)
        acc = fmaf(x[n * 9 + k], w[k * 64 + c], acc);
    out[i] = fmaxf(acc, 0.f);
}

// ---------------- edge counts / inverse counts ----------------
__global__ void k_count(const int* __restrict__ ei, int* __restrict__ cnt) {
    int e = blockIdx.x * 256 + threadIdx.x;
    if (e >= NE) return;
    atomicAdd(&cnt[ei[e]], 1);
}

__global__ void k_rinv(const int* __restrict__ cnt, float* __restrict__ rinv) {
    int n = blockIdx.x * 256 + threadIdx.x;
    if (n >= NN) return;
    rinv[n] = 1.f / fmaxf((float)cnt[n], 1.f);
}

// ---------------- CGConv message pass (fast: transposed weights, float4) ----------------
#define CWAVES 4
#define EPW 4
__launch_bounds__(256, 2)
__global__ void k_conv(const float* __restrict__ xin,
                       const int* __restrict__ ei,
                       const float* __restrict__ ew,
                       const float* __restrict__ wf,
                       const float* __restrict__ bfb,
                       const float* __restrict__ ws,
                       const float* __restrict__ bsb,
                       float* __restrict__ agg) {
    __shared__ __align__(16) float wfT[CD * WST];
    __shared__ __align__(16) float wsT[CD * WST];
    __shared__ __align__(16) float zb[CWAVES][EPW][WST];

    const int tid = threadIdx.x;
    const int lane = tid & 63;
    const int wv = tid >> 6;

    for (int i = tid; i < ZK * CD; i += 256) {
        int k = i >> 6, c = i & 63;
        wfT[c * WST + k] = wf[i];
        wsT[c * WST + k] = ws[i];
    }
    if (tid < CD) { wfT[tid * WST + 131] = 0.f; wsT[tid * WST + 131] = 0.f; }
    __syncthreads();

    const float bfv = bfb[lane];
    const float bsv = bsb[lane];

    const int gw = blockIdx.x * CWAVES + wv;
    const int nw = gridDim.x * CWAVES;

    for (int e0 = gw * EPW; e0 < NE; e0 += nw * EPW) {
        int rows[EPW];
        const int ne = min(EPW, NE - e0);
        for (int j = 0; j < ne; ++j) {
            const int e = e0 + j;
            const int r = ei[e];
            const int cI = ei[NE + e];
            rows[j] = r;
            zb[wv][j][lane]      = xin[r  * 64 + lane];
            zb[wv][j][64 + lane] = xin[cI * 64 + lane];
            if (lane < 3)   zb[wv][j][128 + lane] = ew[e * 3 + lane];
            if (lane == 3)  zb[wv][j][131] = 0.f;
        }
        float accf[EPW], accs[EPW];
        #pragma unroll
        for (int j = 0; j < EPW; ++j) { accf[j] = bfv; accs[j] = bsv; }

        for (int kk = 0; kk < WST; kk += 4) {
            const float4 wfv = *(const float4*)&wfT[lane * WST + kk];
            const float4 wsv = *(const float4*)&wsT[lane * WST + kk];
            #pragma unroll
            for (int j = 0; j < EPW; ++j) {
                const float4 zv = *(const float4*)&zb[wv][j][kk];
                accf[j] = fmaf(zv.x, wfv.x, accf[j]);
                accf[j] = fmaf(zv.y, wfv.y, accf[j]);
                accf[j] = fmaf(zv.z, wfv.z, accf[j]);
                accf[j] = fmaf(zv.w, wfv.w, accf[j]);
                accs[j] = fmaf(zv.x, wsv.x, accs[j]);
                accs[j] = fmaf(zv.y, wsv.y, accs[j]);
                accs[j] = fmaf(zv.z, wsv.z, accs[j]);
                accs[j] = fmaf(zv.w, wsv.w, accs[j]);
            }
        }
        for (int j = 0; j < ne; ++j) {
            const float sg = 1.f / (1.f + expf(-accf[j]));
            const float sp = (accs[j] > 20.f) ? accs[j] : log1pf(expf(accs[j]));
            atomicAdd(&agg[rows[j] * 64 + lane], sg * sp);
        }
    }
}

// ---------------- conv epilogue: out = relu(xin + agg * rinv[n]) ----------------
__global__ void k_finish(const float* __restrict__ xin, const float* __restrict__ agg,
                         const float* __restrict__ rinv, float* __restrict__ out) {
    int i = blockIdx.x * 256 + threadIdx.x;
    if (i >= NN * CD) return;
    out[i] = fmaxf(xin[i] + agg[i] * rinv[i >> 6], 0.f);
}

// ---------------- GRU cell (in-place h update) ----------------
__global__ void k_gru(const float* __restrict__ m, float* __restrict__ h,
                      const float* __restrict__ wih, const float* __restrict__ bih,
                      const float* __restrict__ whh, const float* __restrict__ bhh) {
    __shared__ float ms[4][64], hs[4][64];
    const int tid = threadIdx.x;
    const int g = tid >> 6, c = tid & 63;
    const int n = blockIdx.x * 4 + g;   // NN divisible by 4
    ms[g][c] = m[n * 64 + c];
    hs[g][c] = h[n * 64 + c];
    __syncthreads();
    float air = bih[c], aiz = bih[64 + c], ain = bih[128 + c];
    float ahr = bhh[c], ahz = bhh[64 + c], ahn = bhh[128 + c];
    for (int k = 0; k < 64; ++k) {
        const float mk = ms[g][k], hk = hs[g][k];
        air = fmaf(mk, wih[k * 192 + c], air);
        aiz = fmaf(mk, wih[k * 192 + 64 + c], aiz);
        ain = fmaf(mk, wih[k * 192 + 128 + c], ain);
        ahr = fmaf(hk, whh[k * 192 + c], ahr);
        ahz = fmaf(hk, whh[k * 192 + 64 + c], ahz);
        ahn = fmaf(hk, whh[k * 192 + 128 + c], ahn);
    }
    const float r  = 1.f / (1.f + expf(-(air + ahr)));
    const float zg = 1.f / (1.f + expf(-(aiz + ahz)));
    const float nn_ = tanhf(ain + r * ahn);
    h[n * 64 + c] = (1.f - zg) * nn_ + zg * hs[g][c];
}

// ---------------- first-node-per-graph indices (searchsorted) ----------------
__global__ void k_idx(const int* __restrict__ batch, int* __restrict__ idx) {
    int g = threadIdx.x;
    if (g >= NGRAPH) return;
    int lo = 0, hi = NN;
    while (lo < hi) {
        int mid = (lo + hi) >> 1;
        if (batch[mid] < g) lo = mid + 1; else hi = mid;
    }
    idx[g] = lo;
}

// ---------------- readout head (single block) — FLOAT32 output ----------------
__global__ void k_head(const float* __restrict__ h, const int* __restrict__ idx,
                       const float* __restrict__ fcsw, const float* __restrict__ fcsb,
                       const float* __restrict__ f2cw, const float* __restrict__ f2cb,
                       const float* __restrict__ f3cw, const float* __restrict__ f3cb,
                       const float* __restrict__ f2dw, const float* __restrict__ f2db,
                       const float* __restrict__ f3dw, const float* __restrict__ f3db,
                       float* __restrict__ out) {
    __shared__ float hsel[4096], xgs[4096], xcs[4096], xds[4096];
    const int tid = threadIdx.x;
    for (int i = tid; i < 4096; i += 256) {
        int g = i >> 6, k = i & 63;
        hsel[i] = h[idx[g] * 64 + k];
    }
    __syncthreads();
    for (int i = tid; i < 4096; i += 256) {
        int g = i >> 6, c = i & 63;
        float acc = fcsb[c];
        for (int k = 0; k < 64; ++k) acc = fmaf(hsel[g * 64 + k], fcsw[k * 64 + c], acc);
        xgs[i] = fmaxf(acc, 0.f);
    }
    __syncthreads();
    for (int i = tid; i < 4096; i += 256) {
        int g = i >> 6, c = i & 63;
        float a1 = f2cb[c], a2 = f2db[c];
        for (int k = 0; k < 64; ++k) {
            const float xv = xgs[g * 64 + k];
            a1 = fmaf(xv, f2cw[k * 64 + c], a1);
            a2 = fmaf(xv, f2dw[k * 64 + c], a2);
        }
        xcs[i] = fmaxf(a1, 0.f);
        xds[i] = fmaxf(a2, 0.f);
    }
    __syncthreads();
    if (tid < 128) {
        int g = tid >> 1, j = tid & 1;
        float a = f3cb[j];
        for (int k = 0; k < 64; ++k) a = fmaf(xcs[g * 64 + k], f3cw[k * 2 + j], a);
        out[g * 2 + j] = 1.f / (1.f + expf(-a));
    } else {
        int t = tid - 128, g = t >> 1, j = t & 1;
        float a = f3db[j];
        for (int k = 0; k < 64; ++k) a = fmaf(xds[g * 64 + k], f3dw[k * 2 + j], a);
        out[128 + g * 2 + j] = a;
    }
}

// ---------------- host launcher ----------------
extern "C" void kernel_launch(void* const* d_in, const int* in_sizes, int n_in,
                              void* d_out, int out_size, void* d_ws, size_t ws_size,
                              hipStream_t stream) {
    (void)in_sizes; (void)n_in; (void)out_size; (void)ws_size;
    const float* x    = (const float*)d_in[0];
    const int* ei1    = (const int*)d_in[1];
    const int* ei2    = (const int*)d_in[2];
    const float* w1   = (const float*)d_in[3];
    const float* w2   = (const float*)d_in[4];
    const int* batch  = (const int*)d_in[5];
    const float* fc1w = (const float*)d_in[6];
    const float* fc1b = (const float*)d_in[7];
    const float* lfw  = (const float*)d_in[8];
    const float* lfb  = (const float*)d_in[9];
    const float* lsw  = (const float*)d_in[10];
    const float* lsb  = (const float*)d_in[11];
    const float* wih  = (const float*)d_in[12];
    const float* bih  = (const float*)d_in[13];
    const float* whh  = (const float*)d_in[14];
    const float* bhh  = (const float*)d_in[15];
    const float* fcsw = (const float*)d_in[16];
    const float* fcsb = (const float*)d_in[17];
    const float* f2cw = (const float*)d_in[18];
    const float* f2cb = (const float*)d_in[19];
    const float* f3cw = (const float*)d_in[20];
    const float* f3cb = (const float*)d_in[21];
    const float* f2dw = (const float*)d_in[22];
    const float* f2db = (const float*)d_in[23];
    const float* f3dw = (const float*)d_in[24];
    const float* f3db = (const float*)d_in[25];

    char* ws = (char*)d_ws;
    size_t off = 0;
    auto alloc = [&](size_t bytes) { char* p = ws + off; off += (bytes + 255) & ~size_t(255); return p; };
    float* hbuf  = (float*)alloc(size_t(NN) * CD * 4);
    float* mbuf  = (float*)alloc(size_t(NN) * CD * 4);
    float* agg   = (float*)alloc(size_t(NN) * CD * 4);
    float* rinv1 = (float*)alloc(size_t(NN) * 4);
    float* rinv2 = (float*)alloc(size_t(NN) * 4);
    int*   cnt1  = (int*)alloc(size_t(NN) * 4);
    int*   cnt2  = (int*)alloc(size_t(NN) * 4);
    int*   idx   = (int*)alloc(256);

    const int NB_NC = (NN * CD + 255) / 256;
    const int NB_E  = (NE + 255) / 256;
    const int NB_N  = (NN + 255) / 256;

    hipMemsetAsync(cnt1, 0, size_t(NN) * 4, stream);
    hipMemsetAsync(cnt2, 0, size_t(NN) * 4, stream);
    k_count<<<NB_E, 256, 0, stream>>>(ei1, cnt1);
    k_count<<<NB_E, 256, 0, stream>>>(ei2, cnt2);
    k_rinv<<<NB_N, 256, 0, stream>>>(cnt1, rinv1);
    k_rinv<<<NB_N, 256, 0, stream>>>(cnt2, rinv2);

    k_fc1<<<NB_NC, 256, 0, stream>>>(x, fc1w, fc1b, hbuf);

    const int CONV_BLOCKS = 1024;
    for (int it = 0; it < 3; ++it) {
        hipMemsetAsync(agg, 0, size_t(NN) * CD * 4, stream);
        k_conv<<<CONV_BLOCKS, 256, 0, stream>>>(hbuf, ei2, w2, lfw, lfb, lsw, lsb, agg);
        k_finish<<<NB_NC, 256, 0, stream>>>(hbuf, agg, rinv2, mbuf);
        hipMemsetAsync(agg, 0, size_t(NN) * CD * 4, stream);
        k_conv<<<CONV_BLOCKS, 256, 0, stream>>>(mbuf, ei1, w1, lfw, lfb, lsw, lsb, agg);
        k_finish<<<NB_NC, 256, 0, stream>>>(mbuf, agg, rinv1, mbuf);
        k_gru<<<NN / 4, 256, 0, stream>>>(mbuf, hbuf, wih, bih, whh, bhh);
    }

    k_idx<<<1, 64, 0, stream>>>(batch, idx);
    k_head<<<1, 256, 0, stream>>>(hbuf, idx, fcsw, fcsb, f2cw, f2cb, f3cw, f3cb,
                                  f2dw, f2db, f3dw, f3db, (float*)d_out);
}

// Round 6
// 1318.701 us; speedup vs baseline: 2.4851x; 2.4851x over previous
//
#include <hip/hip_runtime.h>
#include <hip/hip_bf16.h>
#include <math.h>

constexpr int NE = 400000;
constexpr int NN = 40000;
constexpr int CD = 64;
constexpr int NGRAPH = 64;

// ---------------- fc1: x0 = relu(x @ fc1_w + b) ----------------
__global__ void k_fc1(const float* __restrict__ x,
                      const float* __restrict__ w,
                      const float* __restrict__ b,
                      float* __restrict__ out) {
    int i = blockIdx.x * 256 + threadIdx.x;
    if (i >= NN * CD) return;
    int n = i >> 6, c = i & 63;
    float acc = b[c];
    #pragma unroll
    for (int k = 0; k < 9; ++k)
        acc = fmaf(x[n * 9 + k], w[k * 64 + c], acc);
    out[i] = fmaxf(acc, 0.f);
}

// ---------------- edge counts / inverse counts ----------------
__global__ void k_count(const int* __restrict__ ei, int* __restrict__ cnt) {
    int e = blockIdx.x * 256 + threadIdx.x;
    if (e >= NE) return;
    atomicAdd(&cnt[ei[e]], 1);
}

__global__ void k_rinv(const int* __restrict__ cnt, float* __restrict__ rinv) {
    int n = blockIdx.x * 256 + threadIdx.x;
    if (n >= NN) return;
    rinv[n] = 1.f / fmaxf((float)cnt[n], 1.f);
}

// ---------------- node projection: P[n][0:64]=bf+x@Wf_top, [64:128]=x@Wf_bot,
//                  [128:192]=bs+x@Ws_top, [192:256]=x@Ws_bot ----------------
__global__ void k_proj(const float* __restrict__ x,
                       const float* __restrict__ wf, const float* __restrict__ bfp,
                       const float* __restrict__ wsp, const float* __restrict__ bsp,
                       float* __restrict__ P) {
    __shared__ float xs[8][64];
    const int tid = threadIdx.x;
    const int n0 = blockIdx.x * 8;
    for (int i = tid; i < 512; i += 256)
        xs[i >> 6][i & 63] = x[(size_t)(n0 + (i >> 6)) * 64 + (i & 63)];
    __syncthreads();
    const int q = tid >> 6, c = tid & 63;
    const float* __restrict__ wp = ((q & 2) ? wsp : wf) + ((q & 1) ? 64 * 64 : 0) + c;
    const float bias = (q == 0) ? bfp[c] : (q == 2 ? bsp[c] : 0.f);
    float acc[8];
    #pragma unroll
    for (int g = 0; g < 8; ++g) acc[g] = bias;
    for (int k = 0; k < 64; ++k) {
        const float wv = wp[k * 64];
        #pragma unroll
        for (int g = 0; g < 8; ++g) acc[g] = fmaf(xs[g][k], wv, acc[g]);
    }
    #pragma unroll
    for (int g = 0; g < 8; ++g) P[(size_t)(n0 + g) * 256 + tid] = acc[g];
}

// ---------------- per-edge: gather projections, gate, atomic-accumulate ----------------
__global__ void k_edge(const int* __restrict__ ei, const float* __restrict__ ew,
                       const float* __restrict__ P,
                       const float* __restrict__ wfe,   // wf + 128*64 (3x64 edge block)
                       const float* __restrict__ wse,   // ws + 128*64
                       float* __restrict__ agg) {
    const int c = threadIdx.x & 63;
    const int gw = (blockIdx.x * 256 + threadIdx.x) >> 6;
    const int nw = (gridDim.x * 256) >> 6;
    for (int e = gw; e < NE; e += nw) {
        const int r  = ei[e];
        const int cI = ei[NE + e];
        const float* __restrict__ Pr = P + (size_t)r  * 256;
        const float* __restrict__ Pc = P + (size_t)cI * 256;
        float af = Pr[c]       + Pc[64 + c];
        float as = Pr[128 + c] + Pc[192 + c];
        const float e0 = ew[e * 3], e1 = ew[e * 3 + 1], e2 = ew[e * 3 + 2];
        af += e0 * wfe[c] + e1 * wfe[64 + c] + e2 * wfe[128 + c];
        as += e0 * wse[c] + e1 * wse[64 + c] + e2 * wse[128 + c];
        const float sg = 1.f / (1.f + __expf(-af));
        const float sp = (as > 20.f) ? as : __logf(1.f + __expf(as));
        atomicAdd(&agg[(size_t)r * 64 + c], sg * sp);
    }
}

// ---------------- conv epilogue: out = relu(xin + agg * rinv[n]) ----------------
__global__ void k_finish(const float* __restrict__ xin, const float* __restrict__ agg,
                         const float* __restrict__ rinv, float* __restrict__ out) {
    int i = blockIdx.x * 256 + threadIdx.x;
    if (i >= NN * CD) return;
    out[i] = fmaxf(xin[i] + agg[i] * rinv[i >> 6], 0.f);
}

// ---------------- GRU cell (in-place h update) ----------------
__global__ void k_gru(const float* __restrict__ m, float* __restrict__ h,
                      const float* __restrict__ wih, const float* __restrict__ bih,
                      const float* __restrict__ whh, const float* __restrict__ bhh) {
    __shared__ float ms[4][64], hs[4][64];
    const int tid = threadIdx.x;
    const int g = tid >> 6, c = tid & 63;
    const int n = blockIdx.x * 4 + g;   // NN divisible by 4
    ms[g][c] = m[n * 64 + c];
    hs[g][c] = h[n * 64 + c];
    __syncthreads();
    float air = bih[c], aiz = bih[64 + c], ain = bih[128 + c];
    float ahr = bhh[c], ahz = bhh[64 + c], ahn = bhh[128 + c];
    for (int k = 0; k < 64; ++k) {
        const float mk = ms[g][k], hk = hs[g][k];
        air = fmaf(mk, wih[k * 192 + c], air);
        aiz = fmaf(mk, wih[k * 192 + 64 + c], aiz);
        ain = fmaf(mk, wih[k * 192 + 128 + c], ain);
        ahr = fmaf(hk, whh[k * 192 + c], ahr);
        ahz = fmaf(hk, whh[k * 192 + 64 + c], ahz);
        ahn = fmaf(hk, whh[k * 192 + 128 + c], ahn);
    }
    const float r  = 1.f / (1.f + expf(-(air + ahr)));
    const float zg = 1.f / (1.f + expf(-(aiz + ahz)));
    const float nn_ = tanhf(ain + r * ahn);
    h[n * 64 + c] = (1.f - zg) * nn_ + zg * hs[g][c];
}

// ---------------- first-node-per-graph indices (searchsorted) ----------------
__global__ void k_idx(const int* __restrict__ batch, int* __restrict__ idx) {
    int g = threadIdx.x;
    if (g >= NGRAPH) return;
    int lo = 0, hi = NN;
    while (lo < hi) {
        int mid = (lo + hi) >> 1;
        if (batch[mid] < g) lo = mid + 1; else hi = mid;
    }
    idx[g] = lo;
}

// ---------------- readout head (single block) — float32 output ----------------
__global__ void k_head(const float* __restrict__ h, const int* __restrict__ idx,
                       const float* __restrict__ fcsw, const float* __restrict__ fcsb,
                       const float* __restrict__ f2cw, const float* __restrict__ f2cb,
                       const float* __restrict__ f3cw, const float* __restrict__ f3cb,
                       const float* __restrict__ f2dw, const float* __restrict__ f2db,
                       const float* __restrict__ f3dw, const float* __restrict__ f3db,
                       float* __restrict__ out) {
    __shared__ float hsel[4096], xgs[4096], xcs[4096], xds[4096];
    const int tid = threadIdx.x;
    for (int i = tid; i < 4096; i += 256) {
        int g = i >> 6, k = i & 63;
        hsel[i] = h[idx[g] * 64 + k];
    }
    __syncthreads();
    for (int i = tid; i < 4096; i += 256) {
        int g = i >> 6, c = i & 63;
        float acc = fcsb[c];
        for (int k = 0; k < 64; ++k) acc = fmaf(hsel[g * 64 + k], fcsw[k * 64 + c], acc);
        xgs[i] = fmaxf(acc, 0.f);
    }
    __syncthreads();
    for (int i = tid; i < 4096; i += 256) {
        int g = i >> 6, c = i & 63;
        float a1 = f2cb[c], a2 = f2db[c];
        for (int k = 0; k < 64; ++k) {
            const float xv = xgs[g * 64 + k];
            a1 = fmaf(xv, f2cw[k * 64 + c], a1);
            a2 = fmaf(xv, f2dw[k * 64 + c], a2);
        }
        xcs[i] = fmaxf(a1, 0.f);
        xds[i] = fmaxf(a2, 0.f);
    }
    __syncthreads();
    if (tid < 128) {
        int g = tid >> 1, j = tid & 1;
        float a = f3cb[j];
        for (int k = 0; k < 64; ++k) a = fmaf(xcs[g * 64 + k], f3cw[k * 2 + j], a);
        out[g * 2 + j] = 1.f / (1.f + expf(-a));
    } else {
        int t = tid - 128, g = t >> 1, j = t & 1;
        float a = f3db[j];
        for (int k = 0; k < 64; ++k) a = fmaf(xds[g * 64 + k], f3dw[k * 2 + j], a);
        out[128 + g * 2 + j] = a;
    }
}

// ---------------- host launcher ----------------
extern "C" void kernel_launch(void* const* d_in, const int* in_sizes, int n_in,
                              void* d_out, int out_size, void* d_ws, size_t ws_size,
                              hipStream_t stream) {
    (void)in_sizes; (void)n_in; (void)out_size; (void)ws_size;
    const float* x    = (const float*)d_in[0];
    const int* ei1    = (const int*)d_in[1];
    const int* ei2    = (const int*)d_in[2];
    const float* w1   = (const float*)d_in[3];
    const float* w2   = (const float*)d_in[4];
    const int* batch  = (const int*)d_in[5];
    const float* fc1w = (const float*)d_in[6];
    const float* fc1b = (const float*)d_in[7];
    const float* lfw  = (const float*)d_in[8];
    const float* lfb  = (const float*)d_in[9];
    const float* lsw  = (const float*)d_in[10];
    const float* lsb  = (const float*)d_in[11];
    const float* wih  = (const float*)d_in[12];
    const float* bih  = (const float*)d_in[13];
    const float* whh  = (const float*)d_in[14];
    const float* bhh  = (const float*)d_in[15];
    const float* fcsw = (const float*)d_in[16];
    const float* fcsb = (const float*)d_in[17];
    const float* f2cw = (const float*)d_in[18];
    const float* f2cb = (const float*)d_in[19];
    const float* f3cw = (const float*)d_in[20];
    const float* f3cb = (const float*)d_in[21];
    const float* f2dw = (const float*)d_in[22];
    const float* f2db = (const float*)d_in[23];
    const float* f3dw = (const float*)d_in[24];
    const float* f3db = (const float*)d_in[25];

    char* ws = (char*)d_ws;
    size_t off = 0;
    auto alloc = [&](size_t bytes) { char* p = ws + off; off += (bytes + 255) & ~size_t(255); return p; };
    float* P     = (float*)alloc(size_t(NN) * 256 * 4);   // 40.96 MB
    float* hbuf  = (float*)alloc(size_t(NN) * CD * 4);
    float* mbuf  = (float*)alloc(size_t(NN) * CD * 4);
    float* agg   = (float*)alloc(size_t(NN) * CD * 4);
    float* rinv1 = (float*)alloc(size_t(NN) * 4);
    float* rinv2 = (float*)alloc(size_t(NN) * 4);
    int*   cnt1  = (int*)alloc(size_t(NN) * 4);
    int*   cnt2  = (int*)alloc(size_t(NN) * 4);
    int*   idx   = (int*)alloc(256);

    const int NB_NC = (NN * CD + 255) / 256;
    const int NB_E  = (NE + 255) / 256;
    const int NB_N  = (NN + 255) / 256;
    const int EDGE_BLOCKS = 16384;
    const int PROJ_BLOCKS = NN / 8;   // 5000

    const float* lfe = lfw + 128 * 64;   // edge-attr block of lin_f
    const float* lse = lsw + 128 * 64;

    hipMemsetAsync(cnt1, 0, size_t(NN) * 4, stream);
    hipMemsetAsync(cnt2, 0, size_t(NN) * 4, stream);
    k_count<<<NB_E, 256, 0, stream>>>(ei1, cnt1);
    k_count<<<NB_E, 256, 0, stream>>>(ei2, cnt2);
    k_rinv<<<NB_N, 256, 0, stream>>>(cnt1, rinv1);
    k_rinv<<<NB_N, 256, 0, stream>>>(cnt2, rinv2);

    k_fc1<<<NB_NC, 256, 0, stream>>>(x, fc1w, fc1b, hbuf);

    for (int it = 0; it < 3; ++it) {
        // conv A: edges ei2/w2, input hbuf -> mbuf
        k_proj<<<PROJ_BLOCKS, 256, 0, stream>>>(hbuf, lfw, lfb, lsw, lsb, P);
        hipMemsetAsync(agg, 0, size_t(NN) * CD * 4, stream);
        k_edge<<<EDGE_BLOCKS, 256, 0, stream>>>(ei2, w2, P, lfe, lse, agg);
        k_finish<<<NB_NC, 256, 0, stream>>>(hbuf, agg, rinv2, mbuf);
        // conv B: edges ei1/w1, input mbuf -> mbuf
        k_proj<<<PROJ_BLOCKS, 256, 0, stream>>>(mbuf, lfw, lfb, lsw, lsb, P);
        hipMemsetAsync(agg, 0, size_t(NN) * CD * 4, stream);
        k_edge<<<EDGE_BLOCKS, 256, 0, stream>>>(ei1, w1, P, lfe, lse, agg);
        k_finish<<<NB_NC, 256, 0, stream>>>(mbuf, agg, rinv1, mbuf);
        // GRU: h = gru(m, h)
        k_gru<<<NN / 4, 256, 0, stream>>>(mbuf, hbuf, wih, bih, whh, bhh);
    }

    k_idx<<<1, 64, 0, stream>>>(batch, idx);
    k_head<<<1, 256, 0, stream>>>(hbuf, idx, fcsw, fcsb, f2cw, f2cb, f3cw, f3cb,
                                  f2dw, f2db, f3dw, f3db, (float*)d_out);
}

// Round 7
// 1280.147 us; speedup vs baseline: 2.5600x; 1.0301x over previous
//
#include <hip/hip_runtime.h>
#include <hip/hip_bf16.h>
#include <math.h>

constexpr int NE = 400000;
constexpr int NN = 40000;
constexpr int CD = 64;
constexpr int NGRAPH = 64;

// ---------------- fc1: x0 = relu(x @ fc1_w + b) ----------------
__global__ void k_fc1(const float* __restrict__ x,
                      const float* __restrict__ w,
                      const float* __restrict__ b,
                      float* __restrict__ out) {
    int i = blockIdx.x * 256 + threadIdx.x;
    if (i >= NN * CD) return;
    int n = i >> 6, c = i & 63;
    float acc = b[c];
    #pragma unroll
    for (int k = 0; k < 9; ++k)
        acc = fmaf(x[n * 9 + k], w[k * 64 + c], acc);
    out[i] = fmaxf(acc, 0.f);
}

// ---------------- edge counts ----------------
__global__ void k_count(const int* __restrict__ ei, int* __restrict__ cnt) {
    int e = blockIdx.x * 256 + threadIdx.x;
    if (e >= NE) return;
    atomicAdd(&cnt[ei[e]], 1);
}

// ---------------- exclusive prefix sum over counts -> row_start, cursor ----------------
__global__ void k_scan(const int* __restrict__ cnt, int* __restrict__ row_start,
                       int* __restrict__ cursor) {
    __shared__ int part[256];
    const int tid = threadIdx.x;
    const int CH = (NN + 255) / 256;           // 157
    const int s = tid * CH, e = min(s + CH, NN);
    int local = 0;
    for (int i = s; i < e; ++i) local += cnt[i];
    part[tid] = local;
    __syncthreads();
    for (int off = 1; off < 256; off <<= 1) {   // Hillis-Steele inclusive scan
        int v = (tid >= off) ? part[tid - off] : 0;
        __syncthreads();
        part[tid] += v;
        __syncthreads();
    }
    int run = part[tid] - local;                // exclusive
    for (int i = s; i < e; ++i) {
        row_start[i] = run; cursor[i] = run;
        run += cnt[i];
    }
    if (tid == 255) row_start[NN] = NE;
}

// ---------------- scatter edge ids into CSR order ----------------
__global__ void k_scatter(const int* __restrict__ ei, int* __restrict__ cursor,
                          int* __restrict__ perm) {
    int e = blockIdx.x * 256 + threadIdx.x;
    if (e >= NE) return;
    int pos = atomicAdd(&cursor[ei[e]], 1);
    perm[pos] = e;
}

// ---------------- node projection: P[n][0:64]=bf+x@Wf_top, [64:128]=x@Wf_bot,
//                  [128:192]=bs+x@Ws_top, [192:256]=x@Ws_bot ----------------
__global__ void k_proj(const float* __restrict__ x,
                       const float* __restrict__ wf, const float* __restrict__ bfp,
                       const float* __restrict__ wsp, const float* __restrict__ bsp,
                       float* __restrict__ P) {
    __shared__ float xs[8][64];
    const int tid = threadIdx.x;
    const int n0 = blockIdx.x * 8;
    for (int i = tid; i < 512; i += 256)
        xs[i >> 6][i & 63] = x[(size_t)(n0 + (i >> 6)) * 64 + (i & 63)];
    __syncthreads();
    const int q = tid >> 6, c = tid & 63;
    const float* __restrict__ wp = ((q & 2) ? wsp : wf) + ((q & 1) ? 64 * 64 : 0) + c;
    const float bias = (q == 0) ? bfp[c] : (q == 2 ? bsp[c] : 0.f);
    float acc[8];
    #pragma unroll
    for (int g = 0; g < 8; ++g) acc[g] = bias;
    for (int k = 0; k < 64; ++k) {
        const float wv = wp[k * 64];
        #pragma unroll
        for (int g = 0; g < 8; ++g) acc[g] = fmaf(xs[g][k], wv, acc[g]);
    }
    #pragma unroll
    for (int g = 0; g < 8; ++g) P[(size_t)(n0 + g) * 256 + tid] = acc[g];
}

// ---------------- CSR conv: per-row register aggregation + fused finish ----------------
__global__ void k_edge_csr(const int* __restrict__ ei, const float* __restrict__ ew,
                           const float* __restrict__ P,
                           const float* __restrict__ wfe, const float* __restrict__ wse,
                           const int* __restrict__ row_start, const int* __restrict__ perm,
                           const float* __restrict__ xin, float* __restrict__ out) {
    const int c = threadIdx.x & 63;
    const float wf0 = wfe[c], wf1 = wfe[64 + c], wf2 = wfe[128 + c];
    const float ws0 = wse[c], ws1 = wse[64 + c], ws2 = wse[128 + c];
    const int gw = (blockIdx.x * 256 + threadIdx.x) >> 6;
    const int nw = (gridDim.x * 256) >> 6;
    for (int r = gw; r < NN; r += nw) {
        const int base = row_start[r];
        const int deg  = row_start[r + 1] - base;
        const float pf = P[(size_t)r * 256 + c];
        const float ps = P[(size_t)r * 256 + 128 + c];
        float acc = 0.f;
        for (int i = 0; i < deg; ++i) {
            const int e  = perm[base + i];
            const int cI = ei[NE + e];
            const float e0 = ew[e * 3], e1 = ew[e * 3 + 1], e2 = ew[e * 3 + 2];
            const float af = pf + P[(size_t)cI * 256 + 64 + c]  + e0 * wf0 + e1 * wf1 + e2 * wf2;
            const float as = ps + P[(size_t)cI * 256 + 192 + c] + e0 * ws0 + e1 * ws1 + e2 * ws2;
            const float sg = 1.f / (1.f + __expf(-af));
            const float sp = (as > 20.f) ? as : __logf(1.f + __expf(as));
            acc = fmaf(sg, sp, acc);
        }
        const float rinv = 1.f / (float)max(deg, 1);
        out[(size_t)r * 64 + c] = fmaxf(fmaf(acc, rinv, xin[(size_t)r * 64 + c]), 0.f);
    }
}

// ---------------- GRU pass 1: gi = m @ wih + bih  (48 KB weight staged) ----------------
__global__ void k_gemm192(const float* __restrict__ in, const float* __restrict__ w,
                          const float* __restrict__ b, float* __restrict__ out) {
    __shared__ float xs[32 * 65];    // padded: bank = (n + k) & 31
    __shared__ float wS[64 * 192];   // 48 KB
    const int tid = threadIdx.x;
    const int n0 = blockIdx.x * 32;
    for (int i = tid; i < 2048; i += 256)
        xs[(i >> 6) * 65 + (i & 63)] = in[(size_t)n0 * 64 + i];
    for (int i = tid; i < 12288; i += 256) wS[i] = w[i];
    __syncthreads();
    int xoff[24], wcol[24];
    float acc[24];
    #pragma unroll
    for (int j = 0; j < 24; ++j) {
        const int oi = j * 256 + tid;
        xoff[j] = (oi / 192) * 65;
        wcol[j] = oi % 192;
        acc[j] = b[wcol[j]];
    }
    for (int k = 0; k < 64; ++k) {
        #pragma unroll
        for (int j = 0; j < 24; ++j)
            acc[j] = fmaf(xs[xoff[j] + k], wS[k * 192 + wcol[j]], acc[j]);
    }
    #pragma unroll
    for (int j = 0; j < 24; ++j)
        out[(size_t)n0 * 192 + j * 256 + tid] = acc[j];
}

// ---------------- GRU pass 2: gates + combine (whh staged) ----------------
__global__ void k_gru2(const float* __restrict__ gi, float* __restrict__ h,
                       const float* __restrict__ whh, const float* __restrict__ bhh) {
    __shared__ float hs[32 * 65];
    __shared__ float wS[64 * 192];
    const int tid = threadIdx.x;
    const int n0 = blockIdx.x * 32;
    for (int i = tid; i < 2048; i += 256)
        hs[(i >> 6) * 65 + (i & 63)] = h[(size_t)n0 * 64 + i];
    for (int i = tid; i < 12288; i += 256) wS[i] = whh[i];
    __syncthreads();
    const int c = tid & 63, tg = tid >> 6;
    const float br = bhh[c], bz = bhh[64 + c], bn = bhh[128 + c];
    float ar[8], az[8], an[8];
    #pragma unroll
    for (int j = 0; j < 8; ++j) { ar[j] = br; az[j] = bz; an[j] = bn; }
    for (int k = 0; k < 64; ++k) {
        const float wr = wS[k * 192 + c];
        const float wz = wS[k * 192 + 64 + c];
        const float wn = wS[k * 192 + 128 + c];
        #pragma unroll
        for (int j = 0; j < 8; ++j) {
            const float hk = hs[(j * 4 + tg) * 65 + k];
            ar[j] = fmaf(hk, wr, ar[j]);
            az[j] = fmaf(hk, wz, az[j]);
            an[j] = fmaf(hk, wn, an[j]);
        }
    }
    #pragma unroll
    for (int j = 0; j < 8; ++j) {
        const int n = n0 + j * 4 + tg;
        const float gir = gi[(size_t)n * 192 + c];
        const float giz = gi[(size_t)n * 192 + 64 + c];
        const float gin = gi[(size_t)n * 192 + 128 + c];
        const float r  = 1.f / (1.f + __expf(-(gir + ar[j])));
        const float zg = 1.f / (1.f + __expf(-(giz + az[j])));
        const float ng = tanhf(gin + r * an[j]);
        const float hold = hs[(j * 4 + tg) * 65 + c];
        h[(size_t)n * 64 + c] = (1.f - zg) * ng + zg * hold;
    }
}

// ---------------- first-node-per-graph indices (searchsorted) ----------------
__global__ void k_idx(const int* __restrict__ batch, int* __restrict__ idx) {
    int g = threadIdx.x;
    if (g >= NGRAPH) return;
    int lo = 0, hi = NN;
    while (lo < hi) {
        int mid = (lo + hi) >> 1;
        if (batch[mid] < g) lo = mid + 1; else hi = mid;
    }
    idx[g] = lo;
}

// ---------------- readout head: all weights/activations in LDS ----------------
__global__ void k_head(const float* __restrict__ h, const int* __restrict__ idx,
                       const float* __restrict__ fcsw, const float* __restrict__ fcsb,
                       const float* __restrict__ f2cw, const float* __restrict__ f2cb,
                       const float* __restrict__ f3cw, const float* __restrict__ f3cb,
                       const float* __restrict__ f2dw, const float* __restrict__ f2db,
                       const float* __restrict__ f3dw, const float* __restrict__ f3db,
                       float* __restrict__ out) {
    __shared__ float hsB[4096];  // hsel -> xgs
    __shared__ float waB[4096];  // fcsw -> xcs
    __shared__ float wbB[4096];  // f2cw -> xds
    __shared__ float wcB[4096];  // f2dw -> f3 weights
    const int tid = threadIdx.x;
    for (int i = tid; i < 4096; i += 256) {
        int g = i >> 6, k = i & 63;
        hsB[i] = h[(size_t)idx[g] * 64 + k];
        waB[i] = fcsw[i];
        wbB[i] = f2cw[i];
        wcB[i] = f2dw[i];
    }
    __syncthreads();
    // stage 1: xg = relu(hsel @ fcsw + fcsb)
    float v[16];
    #pragma unroll
    for (int j = 0; j < 16; ++j) {
        const int i = j * 256 + tid, g = i >> 6, c = i & 63;
        float a = fcsb[c];
        for (int k = 0; k < 64; ++k) a = fmaf(hsB[g * 64 + k], waB[k * 64 + c], a);
        v[j] = fmaxf(a, 0.f);
    }
    __syncthreads();
    #pragma unroll
    for (int j = 0; j < 16; ++j) hsB[j * 256 + tid] = v[j];   // xgs
    __syncthreads();
    // stage 2: xc, xd
    float vc[16], vd[16];
    #pragma unroll
    for (int j = 0; j < 16; ++j) {
        const int i = j * 256 + tid, g = i >> 6, c = i & 63;
        float a1 = f2cb[c], a2 = f2db[c];
        for (int k = 0; k < 64; ++k) {
            const float xv = hsB[g * 64 + k];
            a1 = fmaf(xv, wbB[k * 64 + c], a1);
            a2 = fmaf(xv, wcB[k * 64 + c], a2);
        }
        vc[j] = fmaxf(a1, 0.f);
        vd[j] = fmaxf(a2, 0.f);
    }
    __syncthreads();
    #pragma unroll
    for (int j = 0; j < 16; ++j) {
        waB[j * 256 + tid] = vc[j];   // xcs
        wbB[j * 256 + tid] = vd[j];   // xds
    }
    if (tid < 128) wcB[tid] = f3cw[tid];           // 64x2
    else           wcB[tid] = f3dw[tid - 128];     // 64x2 at offset 128
    __syncthreads();
    // stage 3
    if (tid < 128) {
        int g = tid >> 1, j = tid & 1;
        float a = f3cb[j];
        for (int k = 0; k < 64; ++k) a = fmaf(waB[g * 64 + k], wcB[k * 2 + j], a);
        out[g * 2 + j] = 1.f / (1.f + expf(-a));
    } else {
        int t = tid - 128, g = t >> 1, j = t & 1;
        float a = f3db[j];
        for (int k = 0; k < 64; ++k) a = fmaf(wbB[g * 64 + k], wcB[128 + k * 2 + j], a);
        out[128 + g * 2 + j] = a;
    }
}

// ---------------- host launcher ----------------
extern "C" void kernel_launch(void* const* d_in, const int* in_sizes, int n_in,
                              void* d_out, int out_size, void* d_ws, size_t ws_size,
                              hipStream_t stream) {
    (void)in_sizes; (void)n_in; (void)out_size; (void)ws_size;
    const float* x    = (const float*)d_in[0];
    const int* ei1    = (const int*)d_in[1];
    const int* ei2    = (const int*)d_in[2];
    const float* w1   = (const float*)d_in[3];
    const float* w2   = (const float*)d_in[4];
    const int* batch  = (const int*)d_in[5];
    const float* fc1w = (const float*)d_in[6];
    const float* fc1b = (const float*)d_in[7];
    const float* lfw  = (const float*)d_in[8];
    const float* lfb  = (const float*)d_in[9];
    const float* lsw  = (const float*)d_in[10];
    const float* lsb  = (const float*)d_in[11];
    const float* wih  = (const float*)d_in[12];
    const float* bih  = (const float*)d_in[13];
    const float* whh  = (const float*)d_in[14];
    const float* bhh  = (const float*)d_in[15];
    const float* fcsw = (const float*)d_in[16];
    const float* fcsb = (const float*)d_in[17];
    const float* f2cw = (const float*)d_in[18];
    const float* f2cb = (const float*)d_in[19];
    const float* f3cw = (const float*)d_in[20];
    const float* f3cb = (const float*)d_in[21];
    const float* f2dw = (const float*)d_in[22];
    const float* f2db = (const float*)d_in[23];
    const float* f3dw = (const float*)d_in[24];
    const float* f3db = (const float*)d_in[25];

    char* ws = (char*)d_ws;
    size_t off = 0;
    auto alloc = [&](size_t bytes) { char* p = ws + off; off += (bytes + 255) & ~size_t(255); return p; };
    float* P     = (float*)alloc(size_t(NN) * 256 * 4);   // 41 MB; reused as gi (30.7 MB) during GRU
    float* hbuf  = (float*)alloc(size_t(NN) * CD * 4);
    float* mbuf  = (float*)alloc(size_t(NN) * CD * 4);
    int*   cnt1  = (int*)alloc(size_t(NN) * 4);
    int*   cnt2  = (int*)alloc(size_t(NN) * 4);
    int*   rs1   = (int*)alloc(size_t(NN + 1) * 4);
    int*   rs2   = (int*)alloc(size_t(NN + 1) * 4);
    int*   cur1  = (int*)alloc(size_t(NN + 1) * 4);
    int*   cur2  = (int*)alloc(size_t(NN + 1) * 4);
    int*   perm1 = (int*)alloc(size_t(NE) * 4);
    int*   perm2 = (int*)alloc(size_t(NE) * 4);
    int*   idx   = (int*)alloc(256);
    float* gi    = P;                                      // alias: P free during GRU

    const int NB_NC = (NN * CD + 255) / 256;
    const int NB_E  = (NE + 255) / 256;
    const int EDGE_BLOCKS = 2048;
    const int PROJ_BLOCKS = NN / 8;    // 5000
    const int GRU_BLOCKS  = NN / 32;   // 1250

    const float* lfe = lfw + 128 * 64;   // edge-attr rows of lin_f
    const float* lse = lsw + 128 * 64;

    // CSR build (once; reused across the 3 iterations)
    hipMemsetAsync(cnt1, 0, size_t(NN) * 4, stream);
    hipMemsetAsync(cnt2, 0, size_t(NN) * 4, stream);
    k_count<<<NB_E, 256, 0, stream>>>(ei1, cnt1);
    k_count<<<NB_E, 256, 0, stream>>>(ei2, cnt2);
    k_scan<<<1, 256, 0, stream>>>(cnt1, rs1, cur1);
    k_scan<<<1, 256, 0, stream>>>(cnt2, rs2, cur2);
    k_scatter<<<NB_E, 256, 0, stream>>>(ei1, cur1, perm1);
    k_scatter<<<NB_E, 256, 0, stream>>>(ei2, cur2, perm2);

    k_fc1<<<NB_NC, 256, 0, stream>>>(x, fc1w, fc1b, hbuf);

    for (int it = 0; it < 3; ++it) {
        // conv A: edges ei2/w2, hbuf -> mbuf
        k_proj<<<PROJ_BLOCKS, 256, 0, stream>>>(hbuf, lfw, lfb, lsw, lsb, P);
        k_edge_csr<<<EDGE_BLOCKS, 256, 0, stream>>>(ei2, w2, P, lfe, lse, rs2, perm2, hbuf, mbuf);
        // conv B: edges ei1/w1, mbuf -> mbuf (in place; safe: neighbor data comes from P)
        k_proj<<<PROJ_BLOCKS, 256, 0, stream>>>(mbuf, lfw, lfb, lsw, lsb, P);
        k_edge_csr<<<EDGE_BLOCKS, 256, 0, stream>>>(ei1, w1, P, lfe, lse, rs1, perm1, mbuf, mbuf);
        // GRU: h = gru(m, h)   (gi aliases P — P is dead here)
        k_gemm192<<<GRU_BLOCKS, 256, 0, stream>>>(mbuf, wih, bih, gi);
        k_gru2<<<GRU_BLOCKS, 256, 0, stream>>>(gi, hbuf, whh, bhh);
    }

    k_idx<<<1, 64, 0, stream>>>(batch, idx);
    k_head<<<1, 256, 0, stream>>>(hbuf, idx, fcsw, fcsb, f2cw, f2cb, f3cw, f3cb,
                                  f2dw, f2db, f3dw, f3db, (float*)d_out);
}

// Round 8
// 1122.640 us; speedup vs baseline: 2.9192x; 1.1403x over previous
//
#include <hip/hip_runtime.h>
#include <hip/hip_bf16.h>
#include <math.h>

constexpr int NE = 400000;
constexpr int NN = 40000;
constexpr int CD = 64;
constexpr int NGRAPH = 64;
constexpr int SCAN_BLOCKS = (NN + 255) / 256;   // 157

// ---------------- fc1: x0 = relu(x @ fc1_w + b) ----------------
__global__ void k_fc1(const float* __restrict__ x,
                      const float* __restrict__ w,
                      const float* __restrict__ b,
                      float* __restrict__ out) {
    int i = blockIdx.x * 256 + threadIdx.x;
    if (i >= NN * CD) return;
    int n = i >> 6, c = i & 63;
    float acc = b[c];
    #pragma unroll
    for (int k = 0; k < 9; ++k)
        acc = fmaf(x[n * 9 + k], w[k * 64 + c], acc);
    out[i] = fmaxf(acc, 0.f);
}

// ---------------- edge counts ----------------
__global__ void k_count(const int* __restrict__ ei, int* __restrict__ cnt) {
    int e = blockIdx.x * 256 + threadIdx.x;
    if (e >= NE) return;
    atomicAdd(&cnt[ei[e]], 1);
}

// ---------------- parallel scan, phase 1: per-block partial sums ----------------
__global__ void k_scan_part(const int* __restrict__ cnt, int* __restrict__ partials) {
    __shared__ int red[256];
    const int tid = threadIdx.x;
    const int i = blockIdx.x * 256 + tid;
    red[tid] = (i < NN) ? cnt[i] : 0;
    __syncthreads();
    for (int s = 128; s > 0; s >>= 1) {
        if (tid < s) red[tid] += red[tid + s];
        __syncthreads();
    }
    if (tid == 0) partials[blockIdx.x] = red[0];
}

// ---------------- phase 2: single-block scan of partials (nblk <= 256) ----------------
__global__ void k_scan_mid(const int* __restrict__ partials, int* __restrict__ offs, int nblk) {
    __shared__ int part[256];
    const int tid = threadIdx.x;
    const int v = (tid < nblk) ? partials[tid] : 0;
    part[tid] = v;
    __syncthreads();
    for (int off = 1; off < 256; off <<= 1) {
        int t = (tid >= off) ? part[tid - off] : 0;
        __syncthreads();
        part[tid] += t;
        __syncthreads();
    }
    if (tid < nblk) offs[tid] = part[tid] - v;   // exclusive
}

// ---------------- phase 3: in-block exclusive scan + base -> row_start, cursor ----------------
__global__ void k_scan_fill(const int* __restrict__ cnt, const int* __restrict__ offs,
                            int* __restrict__ row_start, int* __restrict__ cursor) {
    __shared__ int part[256];
    const int tid = threadIdx.x;
    const int i = blockIdx.x * 256 + tid;
    const int v = (i < NN) ? cnt[i] : 0;
    part[tid] = v;
    __syncthreads();
    for (int off = 1; off < 256; off <<= 1) {
        int t = (tid >= off) ? part[tid - off] : 0;
        __syncthreads();
        part[tid] += t;
        __syncthreads();
    }
    const int excl = part[tid] - v + offs[blockIdx.x];
    if (i < NN) { row_start[i] = excl; cursor[i] = excl; }
    if (i == NN - 1) row_start[NN] = NE;
}

// ---------------- scatter edge ids into CSR order ----------------
__global__ void k_scatter(const int* __restrict__ ei, int* __restrict__ cursor,
                          int* __restrict__ perm) {
    int e = blockIdx.x * 256 + threadIdx.x;
    if (e >= NE) return;
    int pos = atomicAdd(&cursor[ei[e]], 1);
    perm[pos] = e;
}

// ---------------- node projection: P[n][0:64]=bf+x@Wf_top, [64:128]=x@Wf_bot,
//                  [128:192]=bs+x@Ws_top, [192:256]=x@Ws_bot ----------------
__global__ void k_proj(const float* __restrict__ x,
                       const float* __restrict__ wf, const float* __restrict__ bfp,
                       const float* __restrict__ wsp, const float* __restrict__ bsp,
                       float* __restrict__ P) {
    __shared__ float xs[8][64];
    const int tid = threadIdx.x;
    const int n0 = blockIdx.x * 8;
    for (int i = tid; i < 512; i += 256)
        xs[i >> 6][i & 63] = x[(size_t)(n0 + (i >> 6)) * 64 + (i & 63)];
    __syncthreads();
    const int q = tid >> 6, c = tid & 63;
    const float* __restrict__ wp = ((q & 2) ? wsp : wf) + ((q & 1) ? 64 * 64 : 0) + c;
    const float bias = (q == 0) ? bfp[c] : (q == 2 ? bsp[c] : 0.f);
    float acc[8];
    #pragma unroll
    for (int g = 0; g < 8; ++g) acc[g] = bias;
    for (int k = 0; k < 64; ++k) {
        const float wv = wp[k * 64];
        #pragma unroll
        for (int g = 0; g < 8; ++g) acc[g] = fmaf(xs[g][k], wv, acc[g]);
    }
    #pragma unroll
    for (int g = 0; g < 8; ++g) P[(size_t)(n0 + g) * 256 + tid] = acc[g];
}

// ---------------- CSR conv: per-row register aggregation, depth-1 prefetch ----------------
__global__ void k_edge_csr(const int* __restrict__ ei, const float* __restrict__ ew,
                           const float* __restrict__ P,
                           const float* __restrict__ wfe, const float* __restrict__ wse,
                           const int* __restrict__ row_start, const int* __restrict__ perm,
                           const float* __restrict__ xin, float* __restrict__ out) {
    const int c = threadIdx.x & 63;
    const float wf0 = wfe[c], wf1 = wfe[64 + c], wf2 = wfe[128 + c];
    const float ws0 = wse[c], ws1 = wse[64 + c], ws2 = wse[128 + c];
    const int gw = (blockIdx.x * 256 + threadIdx.x) >> 6;
    const int nw = (gridDim.x * 256) >> 6;
    for (int r = gw; r < NN; r += nw) {
        const int base = row_start[r];
        const int deg  = row_start[r + 1] - base;
        const float pf = P[(size_t)r * 256 + c];
        const float ps = P[(size_t)r * 256 + 128 + c];
        float acc = 0.f;
        // prefetch iteration 0
        float Pf_n = 0.f, Ps_n = 0.f, E0_n = 0.f, E1_n = 0.f, E2_n = 0.f;
        if (deg > 0) {
            const int e0_ = perm[base];
            const int cI_ = ei[NE + e0_];
            Pf_n = P[(size_t)cI_ * 256 + 64 + c];
            Ps_n = P[(size_t)cI_ * 256 + 192 + c];
            E0_n = ew[e0_ * 3]; E1_n = ew[e0_ * 3 + 1]; E2_n = ew[e0_ * 3 + 2];
        }
        for (int i = 0; i < deg; ++i) {
            const float Pf = Pf_n, Ps = Ps_n, E0 = E0_n, E1 = E1_n, E2 = E2_n;
            if (i + 1 < deg) {
                const int e_ = perm[base + i + 1];
                const int cI_ = ei[NE + e_];
                Pf_n = P[(size_t)cI_ * 256 + 64 + c];
                Ps_n = P[(size_t)cI_ * 256 + 192 + c];
                E0_n = ew[e_ * 3]; E1_n = ew[e_ * 3 + 1]; E2_n = ew[e_ * 3 + 2];
            }
            const float af = pf + Pf + E0 * wf0 + E1 * wf1 + E2 * wf2;
            const float as = ps + Ps + E0 * ws0 + E1 * ws1 + E2 * ws2;
            const float sg = 1.f / (1.f + __expf(-af));
            const float sp = (as > 20.f) ? as : __logf(1.f + __expf(as));
            acc = fmaf(sg, sp, acc);
        }
        const float rinv = 1.f / (float)max(deg, 1);
        out[(size_t)r * 64 + c] = fmaxf(fmaf(acc, rinv, xin[(size_t)r * 64 + c]), 0.f);
    }
}

// ---------------- GRU pass 1: gi = m @ wih + bih  (48 KB weight staged) ----------------
__global__ void k_gemm192(const float* __restrict__ in, const float* __restrict__ w,
                          const float* __restrict__ b, float* __restrict__ out) {
    __shared__ float xs[32 * 65];
    __shared__ float wS[64 * 192];
    const int tid = threadIdx.x;
    const int n0 = blockIdx.x * 32;
    for (int i = tid; i < 2048; i += 256)
        xs[(i >> 6) * 65 + (i & 63)] = in[(size_t)n0 * 64 + i];
    for (int i = tid; i < 12288; i += 256) wS[i] = w[i];
    __syncthreads();
    int xoff[24], wcol[24];
    float acc[24];
    #pragma unroll
    for (int j = 0; j < 24; ++j) {
        const int oi = j * 256 + tid;
        xoff[j] = (oi / 192) * 65;
        wcol[j] = oi % 192;
        acc[j] = b[wcol[j]];
    }
    for (int k = 0; k < 64; ++k) {
        #pragma unroll
        for (int j = 0; j < 24; ++j)
            acc[j] = fmaf(xs[xoff[j] + k], wS[k * 192 + wcol[j]], acc[j]);
    }
    #pragma unroll
    for (int j = 0; j < 24; ++j)
        out[(size_t)n0 * 192 + j * 256 + tid] = acc[j];
}

// ---------------- GRU pass 2: gates + combine (whh staged) ----------------
__global__ void k_gru2(const float* __restrict__ gi, float* __restrict__ h,
                       const float* __restrict__ whh, const float* __restrict__ bhh) {
    __shared__ float hs[32 * 65];
    __shared__ float wS[64 * 192];
    const int tid = threadIdx.x;
    const int n0 = blockIdx.x * 32;
    for (int i = tid; i < 2048; i += 256)
        hs[(i >> 6) * 65 + (i & 63)] = h[(size_t)n0 * 64 + i];
    for (int i = tid; i < 12288; i += 256) wS[i] = whh[i];
    __syncthreads();
    const int c = tid & 63, tg = tid >> 6;
    const float br = bhh[c], bz = bhh[64 + c], bn = bhh[128 + c];
    float ar[8], az[8], an[8];
    #pragma unroll
    for (int j = 0; j < 8; ++j) { ar[j] = br; az[j] = bz; an[j] = bn; }
    for (int k = 0; k < 64; ++k) {
        const float wr = wS[k * 192 + c];
        const float wz = wS[k * 192 + 64 + c];
        const float wn = wS[k * 192 + 128 + c];
        #pragma unroll
        for (int j = 0; j < 8; ++j) {
            const float hk = hs[(j * 4 + tg) * 65 + k];
            ar[j] = fmaf(hk, wr, ar[j]);
            az[j] = fmaf(hk, wz, az[j]);
            an[j] = fmaf(hk, wn, an[j]);
        }
    }
    #pragma unroll
    for (int j = 0; j < 8; ++j) {
        const int n = n0 + j * 4 + tg;
        const float gir = gi[(size_t)n * 192 + c];
        const float giz = gi[(size_t)n * 192 + 64 + c];
        const float gin = gi[(size_t)n * 192 + 128 + c];
        const float r  = 1.f / (1.f + __expf(-(gir + ar[j])));
        const float zg = 1.f / (1.f + __expf(-(giz + az[j])));
        const float ng = tanhf(gin + r * an[j]);
        const float hold = hs[(j * 4 + tg) * 65 + c];
        h[(size_t)n * 64 + c] = (1.f - zg) * ng + zg * hold;
    }
}

// ---------------- first-node-per-graph indices (searchsorted) ----------------
__global__ void k_idx(const int* __restrict__ batch, int* __restrict__ idx) {
    int g = threadIdx.x;
    if (g >= NGRAPH) return;
    int lo = 0, hi = NN;
    while (lo < hi) {
        int mid = (lo + hi) >> 1;
        if (batch[mid] < g) lo = mid + 1; else hi = mid;
    }
    idx[g] = lo;
}

// ---------------- readout head: all weights/activations in LDS ----------------
__global__ void k_head(const float* __restrict__ h, const int* __restrict__ idx,
                       const float* __restrict__ fcsw, const float* __restrict__ fcsb,
                       const float* __restrict__ f2cw, const float* __restrict__ f2cb,
                       const float* __restrict__ f3cw, const float* __restrict__ f3cb,
                       const float* __restrict__ f2dw, const float* __restrict__ f2db,
                       const float* __restrict__ f3dw, const float* __restrict__ f3db,
                       float* __restrict__ out) {
    __shared__ float hsB[4096];  // hsel -> xgs
    __shared__ float waB[4096];  // fcsw -> xcs
    __shared__ float wbB[4096];  // f2cw -> xds
    __shared__ float wcB[4096];  // f2dw -> f3 weights
    const int tid = threadIdx.x;
    for (int i = tid; i < 4096; i += 256) {
        int g = i >> 6, k = i & 63;
        hsB[i] = h[(size_t)idx[g] * 64 + k];
        waB[i] = fcsw[i];
        wbB[i] = f2cw[i];
        wcB[i] = f2dw[i];
    }
    __syncthreads();
    float v[16];
    #pragma unroll
    for (int j = 0; j < 16; ++j) {
        const int i = j * 256 + tid, g = i >> 6, c = i & 63;
        float a = fcsb[c];
        for (int k = 0; k < 64; ++k) a = fmaf(hsB[g * 64 + k], waB[k * 64 + c], a);
        v[j] = fmaxf(a, 0.f);
    }
    __syncthreads();
    #pragma unroll
    for (int j = 0; j < 16; ++j) hsB[j * 256 + tid] = v[j];   // xgs
    __syncthreads();
    float vc[16], vd[16];
    #pragma unroll
    for (int j = 0; j < 16; ++j) {
        const int i = j * 256 + tid, g = i >> 6, c = i & 63;
        float a1 = f2cb[c], a2 = f2db[c];
        for (int k = 0; k < 64; ++k) {
            const float xv = hsB[g * 64 + k];
            a1 = fmaf(xv, wbB[k * 64 + c], a1);
            a2 = fmaf(xv, wcB[k * 64 + c], a2);
        }
        vc[j] = fmaxf(a1, 0.f);
        vd[j] = fmaxf(a2, 0.f);
    }
    __syncthreads();
    #pragma unroll
    for (int j = 0; j < 16; ++j) {
        waB[j * 256 + tid] = vc[j];   // xcs
        wbB[j * 256 + tid] = vd[j];   // xds
    }
    if (tid < 128) wcB[tid] = f3cw[tid];
    else           wcB[tid] = f3dw[tid - 128];
    __syncthreads();
    if (tid < 128) {
        int g = tid >> 1, j = tid & 1;
        float a = f3cb[j];
        for (int k = 0; k < 64; ++k) a = fmaf(waB[g * 64 + k], wcB[k * 2 + j], a);
        out[g * 2 + j] = 1.f / (1.f + expf(-a));
    } else {
        int t = tid - 128, g = t >> 1, j = t & 1;
        float a = f3db[j];
        for (int k = 0; k < 64; ++k) a = fmaf(wbB[g * 64 + k], wcB[128 + k * 2 + j], a);
        out[128 + g * 2 + j] = a;
    }
}

// ---------------- host launcher ----------------
extern "C" void kernel_launch(void* const* d_in, const int* in_sizes, int n_in,
                              void* d_out, int out_size, void* d_ws, size_t ws_size,
                              hipStream_t stream) {
    (void)in_sizes; (void)n_in; (void)out_size; (void)ws_size;
    const float* x    = (const float*)d_in[0];
    const int* ei1    = (const int*)d_in[1];
    const int* ei2    = (const int*)d_in[2];
    const float* w1   = (const float*)d_in[3];
    const float* w2   = (const float*)d_in[4];
    const int* batch  = (const int*)d_in[5];
    const float* fc1w = (const float*)d_in[6];
    const float* fc1b = (const float*)d_in[7];
    const float* lfw  = (const float*)d_in[8];
    const float* lfb  = (const float*)d_in[9];
    const float* lsw  = (const float*)d_in[10];
    const float* lsb  = (const float*)d_in[11];
    const float* wih  = (const float*)d_in[12];
    const float* bih  = (const float*)d_in[13];
    const float* whh  = (const float*)d_in[14];
    const float* bhh  = (const float*)d_in[15];
    const float* fcsw = (const float*)d_in[16];
    const float* fcsb = (const float*)d_in[17];
    const float* f2cw = (const float*)d_in[18];
    const float* f2cb = (const float*)d_in[19];
    const float* f3cw = (const float*)d_in[20];
    const float* f3cb = (const float*)d_in[21];
    const float* f2dw = (const float*)d_in[22];
    const float* f2db = (const float*)d_in[23];
    const float* f3dw = (const float*)d_in[24];
    const float* f3db = (const float*)d_in[25];

    char* ws = (char*)d_ws;
    size_t off = 0;
    auto alloc = [&](size_t bytes) { char* p = ws + off; off += (bytes + 255) & ~size_t(255); return p; };
    float* P     = (float*)alloc(size_t(NN) * 256 * 4);   // 41 MB; aliased as gi during GRU
    float* hbuf  = (float*)alloc(size_t(NN) * CD * 4);
    float* mbuf  = (float*)alloc(size_t(NN) * CD * 4);
    int*   cnt1  = (int*)alloc(size_t(NN) * 4);
    int*   cnt2  = (int*)alloc(size_t(NN) * 4);
    int*   rs1   = (int*)alloc(size_t(NN + 1) * 4);
    int*   rs2   = (int*)alloc(size_t(NN + 1) * 4);
    int*   cur1  = (int*)alloc(size_t(NN + 1) * 4);
    int*   cur2  = (int*)alloc(size_t(NN + 1) * 4);
    int*   perm1 = (int*)alloc(size_t(NE) * 4);
    int*   perm2 = (int*)alloc(size_t(NE) * 4);
    int*   part1 = (int*)alloc(256 * 4);
    int*   part2 = (int*)alloc(256 * 4);
    int*   offs1 = (int*)alloc(256 * 4);
    int*   offs2 = (int*)alloc(256 * 4);
    int*   idx   = (int*)alloc(256);
    float* gi    = P;

    const int NB_NC = (NN * CD + 255) / 256;
    const int NB_E  = (NE + 255) / 256;
    const int EDGE_BLOCKS = 2048;
    const int PROJ_BLOCKS = NN / 8;    // 5000
    const int GRU_BLOCKS  = NN / 32;   // 1250

    const float* lfe = lfw + 128 * 64;
    const float* lse = lsw + 128 * 64;

    // CSR build (parallel scan)
    hipMemsetAsync(cnt1, 0, size_t(NN) * 4, stream);
    hipMemsetAsync(cnt2, 0, size_t(NN) * 4, stream);
    k_count<<<NB_E, 256, 0, stream>>>(ei1, cnt1);
    k_count<<<NB_E, 256, 0, stream>>>(ei2, cnt2);
    k_scan_part<<<SCAN_BLOCKS, 256, 0, stream>>>(cnt1, part1);
    k_scan_part<<<SCAN_BLOCKS, 256, 0, stream>>>(cnt2, part2);
    k_scan_mid<<<1, 256, 0, stream>>>(part1, offs1, SCAN_BLOCKS);
    k_scan_mid<<<1, 256, 0, stream>>>(part2, offs2, SCAN_BLOCKS);
    k_scan_fill<<<SCAN_BLOCKS, 256, 0, stream>>>(cnt1, offs1, rs1, cur1);
    k_scan_fill<<<SCAN_BLOCKS, 256, 0, stream>>>(cnt2, offs2, rs2, cur2);
    k_scatter<<<NB_E, 256, 0, stream>>>(ei1, cur1, perm1);
    k_scatter<<<NB_E, 256, 0, stream>>>(ei2, cur2, perm2);

    k_fc1<<<NB_NC, 256, 0, stream>>>(x, fc1w, fc1b, hbuf);

    for (int it = 0; it < 3; ++it) {
        k_proj<<<PROJ_BLOCKS, 256, 0, stream>>>(hbuf, lfw, lfb, lsw, lsb, P);
        k_edge_csr<<<EDGE_BLOCKS, 256, 0, stream>>>(ei2, w2, P, lfe, lse, rs2, perm2, hbuf, mbuf);
        k_proj<<<PROJ_BLOCKS, 256, 0, stream>>>(mbuf, lfw, lfb, lsw, lsb, P);
        k_edge_csr<<<EDGE_BLOCKS, 256, 0, stream>>>(ei1, w1, P, lfe, lse, rs1, perm1, mbuf, mbuf);
        k_gemm192<<<GRU_BLOCKS, 256, 0, stream>>>(mbuf, wih, bih, gi);
        k_gru2<<<GRU_BLOCKS, 256, 0, stream>>>(gi, hbuf, whh, bhh);
    }

    k_idx<<<1, 64, 0, stream>>>(batch, idx);
    k_head<<<1, 256, 0, stream>>>(hbuf, idx, fcsw, fcsb, f2cw, f2cb, f3cw, f3cb,
                                  f2dw, f2db, f3dw, f3db, (float*)d_out);
}

// Round 9
// 902.656 us; speedup vs baseline: 3.6306x; 1.2437x over previous
//
#include <hip/hip_runtime.h>
#include <hip/hip_bf16.h>
#include <math.h>

constexpr int NE = 400000;
constexpr int NN = 40000;
constexpr int CD = 64;
constexpr int NGRAPH = 64;
constexpr int SCAN_BLOCKS = (NN + 255) / 256;   // 157

// ---------------- fc1: x0 = relu(x @ fc1_w + b) ----------------
__global__ void k_fc1(const float* __restrict__ x,
                      const float* __restrict__ w,
                      const float* __restrict__ b,
                      float* __restrict__ out) {
    int i = blockIdx.x * 256 + threadIdx.x;
    if (i >= NN * CD) return;
    int n = i >> 6, c = i & 63;
    float acc = b[c];
    #pragma unroll
    for (int k = 0; k < 9; ++k)
        acc = fmaf(x[n * 9 + k], w[k * 64 + c], acc);
    out[i] = fmaxf(acc, 0.f);
}

// ---------------- edge counts ----------------
__global__ void k_count(const int* __restrict__ ei, int* __restrict__ cnt) {
    int e = blockIdx.x * 256 + threadIdx.x;
    if (e >= NE) return;
    atomicAdd(&cnt[ei[e]], 1);
}

// ---------------- parallel scan, phase 1: per-block partial sums ----------------
__global__ void k_scan_part(const int* __restrict__ cnt, int* __restrict__ partials) {
    __shared__ int red[256];
    const int tid = threadIdx.x;
    const int i = blockIdx.x * 256 + tid;
    red[tid] = (i < NN) ? cnt[i] : 0;
    __syncthreads();
    for (int s = 128; s > 0; s >>= 1) {
        if (tid < s) red[tid] += red[tid + s];
        __syncthreads();
    }
    if (tid == 0) partials[blockIdx.x] = red[0];
}

// ---------------- phase 2: single-block scan of partials (nblk <= 256) ----------------
__global__ void k_scan_mid(const int* __restrict__ partials, int* __restrict__ offs, int nblk) {
    __shared__ int part[256];
    const int tid = threadIdx.x;
    const int v = (tid < nblk) ? partials[tid] : 0;
    part[tid] = v;
    __syncthreads();
    for (int off = 1; off < 256; off <<= 1) {
        int t = (tid >= off) ? part[tid - off] : 0;
        __syncthreads();
        part[tid] += t;
        __syncthreads();
    }
    if (tid < nblk) offs[tid] = part[tid] - v;   // exclusive
}

// ---------------- phase 3: in-block exclusive scan + base -> row_start, cursor ----------------
__global__ void k_scan_fill(const int* __restrict__ cnt, const int* __restrict__ offs,
                            int* __restrict__ row_start, int* __restrict__ cursor) {
    __shared__ int part[256];
    const int tid = threadIdx.x;
    const int i = blockIdx.x * 256 + tid;
    const int v = (i < NN) ? cnt[i] : 0;
    part[tid] = v;
    __syncthreads();
    for (int off = 1; off < 256; off <<= 1) {
        int t = (tid >= off) ? part[tid - off] : 0;
        __syncthreads();
        part[tid] += t;
        __syncthreads();
    }
    const int excl = part[tid] - v + offs[blockIdx.x];
    if (i < NN) { row_start[i] = excl; cursor[i] = excl; }
    if (i == NN - 1) row_start[NN] = NE;
}

// ---------------- scatter edge ids into CSR order ----------------
__global__ void k_scatter(const int* __restrict__ ei, int* __restrict__ cursor,
                          int* __restrict__ perm) {
    int e = blockIdx.x * 256 + threadIdx.x;
    if (e >= NE) return;
    int pos = atomicAdd(&cursor[ei[e]], 1);
    perm[pos] = e;
}

// ---------------- node projection: P[n][0:64]=bf+x@Wf_top, [64:128]=x@Wf_bot,
//                  [128:192]=bs+x@Ws_top, [192:256]=x@Ws_bot ----------------
__global__ void k_proj(const float* __restrict__ x,
                       const float* __restrict__ wf, const float* __restrict__ bfp,
                       const float* __restrict__ wsp, const float* __restrict__ bsp,
                       float* __restrict__ P) {
    __shared__ float xs[8][64];
    const int tid = threadIdx.x;
    const int n0 = blockIdx.x * 8;
    for (int i = tid; i < 512; i += 256)
        xs[i >> 6][i & 63] = x[(size_t)(n0 + (i >> 6)) * 64 + (i & 63)];
    __syncthreads();
    const int q = tid >> 6, c = tid & 63;
    const float* __restrict__ wp = ((q & 2) ? wsp : wf) + ((q & 1) ? 64 * 64 : 0) + c;
    const float bias = (q == 0) ? bfp[c] : (q == 2 ? bsp[c] : 0.f);
    float acc[8];
    #pragma unroll
    for (int g = 0; g < 8; ++g) acc[g] = bias;
    for (int k = 0; k < 64; ++k) {
        const float wv = wp[k * 64];
        #pragma unroll
        for (int g = 0; g < 8; ++g) acc[g] = fmaf(xs[g][k], wv, acc[g]);
    }
    #pragma unroll
    for (int g = 0; g < 8; ++g) P[(size_t)(n0 + g) * 256 + tid] = acc[g];
}

// ---------------- CSR conv: per-row register aggregation, depth-1 prefetch ----------------
__global__ void k_edge_csr(const int* __restrict__ ei, const float* __restrict__ ew,
                           const float* __restrict__ P,
                           const float* __restrict__ wfe, const float* __restrict__ wse,
                           const int* __restrict__ row_start, const int* __restrict__ perm,
                           const float* __restrict__ xin, float* __restrict__ out) {
    const int c = threadIdx.x & 63;
    const float wf0 = wfe[c], wf1 = wfe[64 + c], wf2 = wfe[128 + c];
    const float ws0 = wse[c], ws1 = wse[64 + c], ws2 = wse[128 + c];
    const int gw = (blockIdx.x * 256 + threadIdx.x) >> 6;
    const int nw = (gridDim.x * 256) >> 6;
    for (int r = gw; r < NN; r += nw) {
        const int base = row_start[r];
        const int deg  = row_start[r + 1] - base;
        const float pf = P[(size_t)r * 256 + c];
        const float ps = P[(size_t)r * 256 + 128 + c];
        float acc = 0.f;
        float Pf_n = 0.f, Ps_n = 0.f, E0_n = 0.f, E1_n = 0.f, E2_n = 0.f;
        if (deg > 0) {
            const int e0_ = perm[base];
            const int cI_ = ei[NE + e0_];
            Pf_n = P[(size_t)cI_ * 256 + 64 + c];
            Ps_n = P[(size_t)cI_ * 256 + 192 + c];
            E0_n = ew[e0_ * 3]; E1_n = ew[e0_ * 3 + 1]; E2_n = ew[e0_ * 3 + 2];
        }
        for (int i = 0; i < deg; ++i) {
            const float Pf = Pf_n, Ps = Ps_n, E0 = E0_n, E1 = E1_n, E2 = E2_n;
            if (i + 1 < deg) {
                const int e_ = perm[base + i + 1];
                const int cI_ = ei[NE + e_];
                Pf_n = P[(size_t)cI_ * 256 + 64 + c];
                Ps_n = P[(size_t)cI_ * 256 + 192 + c];
                E0_n = ew[e_ * 3]; E1_n = ew[e_ * 3 + 1]; E2_n = ew[e_ * 3 + 2];
            }
            const float af = pf + Pf + E0 * wf0 + E1 * wf1 + E2 * wf2;
            const float as = ps + Ps + E0 * ws0 + E1 * ws1 + E2 * ws2;
            const float sg = 1.f / (1.f + __expf(-af));
            const float sp = (as > 20.f) ? as : __logf(1.f + __expf(as));
            acc = fmaf(sg, sp, acc);
        }
        const float rinv = 1.f / (float)max(deg, 1);
        out[(size_t)r * 64 + c] = fmaxf(fmaf(acc, rinv, xin[(size_t)r * 64 + c]), 0.f);
    }
}

// ---------------- fused GRU: h = GRU(m, h), weights from L2 ----------------
__global__ void k_gru_fused(const float* __restrict__ m, float* __restrict__ h,
                            const float* __restrict__ wih, const float* __restrict__ bih,
                            const float* __restrict__ whh, const float* __restrict__ bhh) {
    __shared__ float ms[32 * 65], hs[32 * 65];
    const int tid = threadIdx.x;
    const int n0 = blockIdx.x * 32;
    for (int i = tid; i < 2048; i += 256) {
        ms[(i >> 6) * 65 + (i & 63)] = m[(size_t)n0 * 64 + i];
        hs[(i >> 6) * 65 + (i & 63)] = h[(size_t)n0 * 64 + i];
    }
    __syncthreads();
    const int c = tid & 63, tg = tid >> 6;
    float ir[8], iz[8], inn[8], hr[8], hz[8], hn[8];
    #pragma unroll
    for (int j = 0; j < 8; ++j) { ir[j]=0.f; iz[j]=0.f; inn[j]=0.f; hr[j]=0.f; hz[j]=0.f; hn[j]=0.f; }
    for (int k = 0; k < 64; ++k) {
        const float wir = wih[k * 192 + c];
        const float wiz = wih[k * 192 + 64 + c];
        const float win = wih[k * 192 + 128 + c];
        const float whr = whh[k * 192 + c];
        const float whz = whh[k * 192 + 64 + c];
        const float whn = whh[k * 192 + 128 + c];
        #pragma unroll
        for (int j = 0; j < 8; ++j) {
            const float mk = ms[(j * 4 + tg) * 65 + k];
            const float hk = hs[(j * 4 + tg) * 65 + k];
            ir[j]  = fmaf(mk, wir, ir[j]);
            iz[j]  = fmaf(mk, wiz, iz[j]);
            inn[j] = fmaf(mk, win, inn[j]);
            hr[j]  = fmaf(hk, whr, hr[j]);
            hz[j]  = fmaf(hk, whz, hz[j]);
            hn[j]  = fmaf(hk, whn, hn[j]);
        }
    }
    const float bir = bih[c], biz = bih[64 + c], bin = bih[128 + c];
    const float bhr = bhh[c], bhz = bhh[64 + c], bhn = bhh[128 + c];
    #pragma unroll
    for (int j = 0; j < 8; ++j) {
        const int n = n0 + j * 4 + tg;
        const float r  = 1.f / (1.f + __expf(-((ir[j] + bir) + (hr[j] + bhr))));
        const float zg = 1.f / (1.f + __expf(-((iz[j] + biz) + (hz[j] + bhz))));
        const float ng = tanhf((inn[j] + bin) + r * (hn[j] + bhn));
        h[(size_t)n * 64 + c] = (1.f - zg) * ng + zg * hs[(j * 4 + tg) * 65 + c];
    }
}

// ---------------- first-node-per-graph indices (searchsorted) ----------------
__global__ void k_idx(const int* __restrict__ batch, int* __restrict__ idx) {
    int g = threadIdx.x;
    if (g >= NGRAPH) return;
    int lo = 0, hi = NN;
    while (lo < hi) {
        int mid = (lo + hi) >> 1;
        if (batch[mid] < g) lo = mid + 1; else hi = mid;
    }
    idx[g] = lo;
}

// ---------------- readout head: all weights/activations in LDS ----------------
__global__ void k_head(const float* __restrict__ h, const int* __restrict__ idx,
                       const float* __restrict__ fcsw, const float* __restrict__ fcsb,
                       const float* __restrict__ f2cw, const float* __restrict__ f2cb,
                       const float* __restrict__ f3cw, const float* __restrict__ f3cb,
                       const float* __restrict__ f2dw, const float* __restrict__ f2db,
                       const float* __restrict__ f3dw, const float* __restrict__ f3db,
                       float* __restrict__ out) {
    __shared__ float hsB[4096];  // hsel -> xgs
    __shared__ float waB[4096];  // fcsw -> xcs
    __shared__ float wbB[4096];  // f2cw -> xds
    __shared__ float wcB[4096];  // f2dw -> f3 weights
    const int tid = threadIdx.x;
    for (int i = tid; i < 4096; i += 256) {
        int g = i >> 6, k = i & 63;
        hsB[i] = h[(size_t)idx[g] * 64 + k];
        waB[i] = fcsw[i];
        wbB[i] = f2cw[i];
        wcB[i] = f2dw[i];
    }
    __syncthreads();
    float v[16];
    #pragma unroll
    for (int j = 0; j < 16; ++j) {
        const int i = j * 256 + tid, g = i >> 6, c = i & 63;
        float a = fcsb[c];
        for (int k = 0; k < 64; ++k) a = fmaf(hsB[g * 64 + k], waB[k * 64 + c], a);
        v[j] = fmaxf(a, 0.f);
    }
    __syncthreads();
    #pragma unroll
    for (int j = 0; j < 16; ++j) hsB[j * 256 + tid] = v[j];   // xgs
    __syncthreads();
    float vc[16], vd[16];
    #pragma unroll
    for (int j = 0; j < 16; ++j) {
        const int i = j * 256 + tid, g = i >> 6, c = i & 63;
        float a1 = f2cb[c], a2 = f2db[c];
        for (int k = 0; k < 64; ++k) {
            const float xv = hsB[g * 64 + k];
            a1 = fmaf(xv, wbB[k * 64 + c], a1);
            a2 = fmaf(xv, wcB[k * 64 + c], a2);
        }
        vc[j] = fmaxf(a1, 0.f);
        vd[j] = fmaxf(a2, 0.f);
    }
    __syncthreads();
    #pragma unroll
    for (int j = 0; j < 16; ++j) {
        waB[j * 256 + tid] = vc[j];   // xcs
        wbB[j * 256 + tid] = vd[j];   // xds
    }
    if (tid < 128) wcB[tid] = f3cw[tid];
    else           wcB[tid] = f3dw[tid - 128];
    __syncthreads();
    if (tid < 128) {
        int g = tid >> 1, j = tid & 1;
        float a = f3cb[j];
        for (int k = 0; k < 64; ++k) a = fmaf(waB[g * 64 + k], wcB[k * 2 + j], a);
        out[g * 2 + j] = 1.f / (1.f + expf(-a));
    } else {
        int t = tid - 128, g = t >> 1, j = t & 1;
        float a = f3db[j];
        for (int k = 0; k < 64; ++k) a = fmaf(wbB[g * 64 + k], wcB[128 + k * 2 + j], a);
        out[128 + g * 2 + j] = a;
    }
}

// ---------------- host launcher ----------------
extern "C" void kernel_launch(void* const* d_in, const int* in_sizes, int n_in,
                              void* d_out, int out_size, void* d_ws, size_t ws_size,
                              hipStream_t stream) {
    (void)in_sizes; (void)n_in; (void)out_size; (void)ws_size;
    const float* x    = (const float*)d_in[0];
    const int* ei1    = (const int*)d_in[1];
    const int* ei2    = (const int*)d_in[2];
    const float* w1   = (const float*)d_in[3];
    const float* w2   = (const float*)d_in[4];
    const int* batch  = (const int*)d_in[5];
    const float* fc1w = (const float*)d_in[6];
    const float* fc1b = (const float*)d_in[7];
    const float* lfw  = (const float*)d_in[8];
    const float* lfb  = (const float*)d_in[9];
    const float* lsw  = (const float*)d_in[10];
    const float* lsb  = (const float*)d_in[11];
    const float* wih  = (const float*)d_in[12];
    const float* bih  = (const float*)d_in[13];
    const float* whh  = (const float*)d_in[14];
    const float* bhh  = (const float*)d_in[15];
    const float* fcsw = (const float*)d_in[16];
    const float* fcsb = (const float*)d_in[17];
    const float* f2cw = (const float*)d_in[18];
    const float* f2cb = (const float*)d_in[19];
    const float* f3cw = (const float*)d_in[20];
    const float* f3cb = (const float*)d_in[21];
    const float* f2dw = (const float*)d_in[22];
    const float* f2db = (const float*)d_in[23];
    const float* f3dw = (const float*)d_in[24];
    const float* f3db = (const float*)d_in[25];

    char* ws = (char*)d_ws;
    size_t off = 0;
    auto alloc = [&](size_t bytes) { char* p = ws + off; off += (bytes + 255) & ~size_t(255); return p; };
    float* P     = (float*)alloc(size_t(NN) * 256 * 4);   // 41 MB
    float* hbuf  = (float*)alloc(size_t(NN) * CD * 4);
    float* mbuf  = (float*)alloc(size_t(NN) * CD * 4);
    int*   cnt1  = (int*)alloc(size_t(NN) * 4);
    int*   cnt2  = (int*)alloc(size_t(NN) * 4);
    int*   rs1   = (int*)alloc(size_t(NN + 1) * 4);
    int*   rs2   = (int*)alloc(size_t(NN + 1) * 4);
    int*   cur1  = (int*)alloc(size_t(NN + 1) * 4);
    int*   cur2  = (int*)alloc(size_t(NN + 1) * 4);
    int*   perm1 = (int*)alloc(size_t(NE) * 4);
    int*   perm2 = (int*)alloc(size_t(NE) * 4);
    int*   part1 = (int*)alloc(256 * 4);
    int*   part2 = (int*)alloc(256 * 4);
    int*   offs1 = (int*)alloc(256 * 4);
    int*   offs2 = (int*)alloc(256 * 4);
    int*   idx   = (int*)alloc(256);

    const int NB_NC = (NN * CD + 255) / 256;
    const int NB_E  = (NE + 255) / 256;
    const int EDGE_BLOCKS = 2048;
    const int PROJ_BLOCKS = NN / 8;    // 5000
    const int GRU_BLOCKS  = NN / 32;   // 1250

    const float* lfe = lfw + 128 * 64;
    const float* lse = lsw + 128 * 64;

    // CSR build (parallel scan)
    hipMemsetAsync(cnt1, 0, size_t(NN) * 4, stream);
    hipMemsetAsync(cnt2, 0, size_t(NN) * 4, stream);
    k_count<<<NB_E, 256, 0, stream>>>(ei1, cnt1);
    k_count<<<NB_E, 256, 0, stream>>>(ei2, cnt2);
    k_scan_part<<<SCAN_BLOCKS, 256, 0, stream>>>(cnt1, part1);
    k_scan_part<<<SCAN_BLOCKS, 256, 0, stream>>>(cnt2, part2);
    k_scan_mid<<<1, 256, 0, stream>>>(part1, offs1, SCAN_BLOCKS);
    k_scan_mid<<<1, 256, 0, stream>>>(part2, offs2, SCAN_BLOCKS);
    k_scan_fill<<<SCAN_BLOCKS, 256, 0, stream>>>(cnt1, offs1, rs1, cur1);
    k_scan_fill<<<SCAN_BLOCKS, 256, 0, stream>>>(cnt2, offs2, rs2, cur2);
    k_scatter<<<NB_E, 256, 0, stream>>>(ei1, cur1, perm1);
    k_scatter<<<NB_E, 256, 0, stream>>>(ei2, cur2, perm2);

    k_fc1<<<NB_NC, 256, 0, stream>>>(x, fc1w, fc1b, hbuf);

    for (int it = 0; it < 3; ++it) {
        k_proj<<<PROJ_BLOCKS, 256, 0, stream>>>(hbuf, lfw, lfb, lsw, lsb, P);
        k_edge_csr<<<EDGE_BLOCKS, 256, 0, stream>>>(ei2, w2, P, lfe, lse, rs2, perm2, hbuf, mbuf);
        k_proj<<<PROJ_BLOCKS, 256, 0, stream>>>(mbuf, lfw, lfb, lsw, lsb, P);
        k_edge_csr<<<EDGE_BLOCKS, 256, 0, stream>>>(ei1, w1, P, lfe, lse, rs1, perm1, mbuf, mbuf);
        k_gru_fused<<<GRU_BLOCKS, 256, 0, stream>>>(mbuf, hbuf, wih, bih, whh, bhh);
    }

    k_idx<<<1, 64, 0, stream>>>(batch, idx);
    k_head<<<1, 256, 0, stream>>>(hbuf, idx, fcsw, fcsb, f2cw, f2cb, f3cw, f3cb,
                                  f2dw, f2db, f3dw, f3db, (float*)d_out);
}